// Round 20
// baseline (134.993 us; speedup 1.0000x reference)
//
#include <hip/hip_runtime.h>
#include <hip/hip_bf16.h>
#include <stdint.h>

typedef unsigned short u16;
typedef __attribute__((ext_vector_type(4))) float f32x4;
typedef __attribute__((ext_vector_type(8))) short s16x8;
typedef __attribute__((ext_vector_type(4))) unsigned short u16x4;
typedef __attribute__((ext_vector_type(4))) float fvec4;

#define NH 12
#define DH 64
#define HID 768
#define SEQ 197
#define VP 224            // padded seq cols for Vt slab (global)
#define NREL 732
#define BATCH 64
#define MROWS (BATCH*SEQ) // 12608
#define NCAT (3*HID)      // 2304
#define BK 64
#define MT 99             // grid tiles in M (99*128 = 12672 >= 12608)
#define NT 18             // grid tiles in N (18*128 = 2304)
#define NWG (MT*NT)       // 1782
#define QKSTRIDE (SEQ*DH) // 12608 u16 per bh slab (tight)

// prep_all block ranges
#define PB_X 4728                 // conv_x: 4728*256*8 = 12608*768
#define PB_W (PB_X + 432)         // conv_w: 36*12 tiles
#define PB_B (PB_W + 9)           // conv_b
#define PB_E (PB_B + 507)         // bias tiles: 12*13*13*64 = 129,792 = 507*256 exact

static __device__ __forceinline__ u16 f2bf(float f) {
  union { float f; uint32_t u; } v; v.f = f;
  uint32_t u = v.u;
  return (u16)((u + 0x7FFFu + ((u >> 16) & 1u)) >> 16);
}
static __device__ __forceinline__ float bf2f(u16 v) {
  union { uint32_t u; float f; } x; x.u = ((uint32_t)v) << 16; return x.f;
}

// ---------------- fused prep: conv_x | conv_w | conv_b | expand_bias(tiled) ----------------
__global__ __launch_bounds__(256) void prep_all(const float* __restrict__ x,
                                                const float* __restrict__ Wq, const float* __restrict__ Wk,
                                                const float* __restrict__ Wv, const float* __restrict__ bq,
                                                const float* __restrict__ bv, const float* __restrict__ btab,
                                                u16* __restrict__ xb, u16* __restrict__ Wt,
                                                float* __restrict__ bc, u16* __restrict__ Bxt) {
  __shared__ float t[64][65];
  const int bi = blockIdx.x;
  const int tid = threadIdx.x;
  if (bi < PB_X) {
    // hidden fp32 -> bf16, 8 elems/thread
    int i = bi * 256 + tid;
    fvec4 a = ((const fvec4*)x)[2 * i];
    fvec4 b = ((const fvec4*)x)[2 * i + 1];
    s16x8 r;
    r[0] = (short)f2bf(a[0]); r[1] = (short)f2bf(a[1]); r[2] = (short)f2bf(a[2]); r[3] = (short)f2bf(a[3]);
    r[4] = (short)f2bf(b[0]); r[5] = (short)f2bf(b[1]); r[6] = (short)f2bf(b[2]); r[7] = (short)f2bf(b[3]);
    ((s16x8*)xb)[i] = r;
  } else if (bi < PB_W) {
    // W's -> transposed concat bf16 [NCAT][HID]
    int f = bi - PB_X;
    int n0 = (f % 36) * 64, k0 = (f / 36) * 64;
    int m = n0 / HID;
    const float* W = (m == 0) ? Wq : ((m == 1) ? Wk : Wv);
    int nn0 = n0 - m * HID;
    for (int i = tid; i < 64 * 64; i += 256) {
      int r = i >> 6, c = i & 63;
      t[r][c] = W[(size_t)(k0 + r) * HID + nn0 + c];
    }
    __syncthreads();
    for (int i = tid; i < 64 * 64; i += 256) {
      int r = i >> 6, c = i & 63;
      Wt[(size_t)(n0 + r) * HID + k0 + c] = f2bf(t[c][r]);
    }
  } else if (bi < PB_B) {
    int i = (bi - PB_W) * 256 + tid;
    if (i < NCAT) {
      int m = i / HID, r = i - m * HID;
      bc[i] = (m == 0) ? bq[r] : ((m == 2) ? bv[r] : 0.f);
    }
  } else {
    // bias tiles: entry (h, qf, kf, lane) -> u16x4 of bias(q = qf*16+lg*4+j, k = kf*16+li)
    int i = (bi - PB_B) * 256 + tid;       // < 129,792 exact
    int h = i / (13 * 13 * 64);
    int rem = i - h * (13 * 13 * 64);
    int qf = rem / (13 * 64);
    int rem2 = rem - qf * (13 * 64);
    int kf = rem2 >> 6, lane = rem2 & 63;
    int li = lane & 15, lg = lane >> 4;
    int k = kf * 16 + li;
    u16x4 outv;
#pragma unroll
    for (int j = 0; j < 4; ++j) {
      int q = qf * 16 + lg * 4 + j;
      float v;
      if (k >= SEQ) v = -1e30f;            // mask padded k (incl. cross-slab garbage)
      else if (q >= SEQ) v = 0.f;          // padded q rows: outputs discarded
      else {
        int idx;
        if (q == 0) idx = (k == 0) ? 731 : 729;
        else if (k == 0) idx = 730;
        else {
          int iq = (q - 1) / 14, jq = (q - 1) % 14;
          int ik = (k - 1) / 14, jk = (k - 1) % 14;
          idx = (iq - ik + 13) * 27 + (jq - jk + 13);
        }
        v = btab[(size_t)idx * NH + h];
      }
      outv[j] = f2bf(v);
    }
    ((u16x4*)Bxt)[i] = outv;
  }
}

// ---------------- fused QKV GEMM (r12/r15-proven: ~73 us, fused V-transpose epilogue) ----------------
static __device__ __forceinline__ void stage128(const u16* __restrict__ gbase, int grow0, int growmax,
                                                u16* lds, int w, int l) {
#pragma unroll
  for (int i = 0; i < 4; ++i) {
    int ch = w * 4 + i;                    // wave-uniform 0..15
    int r = ch * 8 + (l >> 3);
    int grow = grow0 + r; if (grow > growmax) grow = growmax;
    int c = (l & 7) ^ (l >> 3);            // inverse swizzle on source
    const u16* g = gbase + (size_t)grow * HID + c * 8;
    __builtin_amdgcn_global_load_lds((const __attribute__((address_space(1))) void*)g,
                                     (__attribute__((address_space(3))) void*)(lds + ch * 512),
                                     16, 0, 0);
  }
}

static __device__ __forceinline__ void compute128(const u16* As, const u16* Bs, int wr, int wc,
                                                  int li, int lg, f32x4 acc[4][4]) {
#pragma unroll
  for (int kk = 0; kk < 2; ++kk) {
    s16x8 af[4], bf[4];
#pragma unroll
    for (int mi = 0; mi < 4; ++mi) {
      int r = wr * 64 + mi * 16 + li;
      int c = (kk * 4 + lg) ^ (r & 7);
      af[mi] = *(const s16x8*)((const char*)As + r * 128 + c * 16);
    }
#pragma unroll
    for (int ni = 0; ni < 4; ++ni) {
      int r = wc * 64 + ni * 16 + li;
      int c = (kk * 4 + lg) ^ (r & 7);
      bf[ni] = *(const s16x8*)((const char*)Bs + r * 128 + c * 16);
    }
#pragma unroll
    for (int mi = 0; mi < 4; ++mi)
#pragma unroll
      for (int ni = 0; ni < 4; ++ni)
        acc[mi][ni] = __builtin_amdgcn_mfma_f32_16x16x32_bf16(af[mi], bf[ni], acc[mi][ni], 0, 0, 0);
  }
}

__global__ __launch_bounds__(256, 2) void qkv_gemm(const u16* __restrict__ Xb, const u16* __restrict__ Wt,
                                                   const float* __restrict__ bc, u16* __restrict__ Qw,
                                                   u16* __restrict__ Kw, u16* __restrict__ Vt) {
  __shared__ u16 LDSU[32768];               // 64 KiB union: staging buffers / V-transpose
  u16* As0 = LDSU;
  u16* Bs0 = LDSU + 8192;
  u16* As1 = LDSU + 16384;
  u16* Bs1 = LDSU + 24576;
  const int tid = threadIdx.x;
  const int w = tid >> 6, l = tid & 63;
  const int wr = w >> 1, wc = w & 1;        // 2x2 wave grid, 64x64 per wave
  const int lg = l >> 4, li = l & 15;

  // bijective XCD chunking (m204): nwg=1782, q=222, r=6
  const int lin = blockIdx.x;
  const int xcd = lin & 7;
  const int pos = lin >> 3;
  const int work = (xcd < 6 ? xcd * 223 : 6 * 223 + (xcd - 6) * 222) + pos;
  const int mt = work / NT, nt = work - mt * NT;
  const int arow0 = mt * 128, brow0 = nt * 128;

  f32x4 acc[4][4] = {};

  stage128(Xb, arow0, MROWS - 1, As0, w, l);
  stage128(Wt, brow0, NCAT - 1, Bs0, w, l);
  __syncthreads();

  for (int kt2 = 0; kt2 < 6; ++kt2) {
    const int kt = kt2 * 2;
    stage128(Xb + (kt + 1) * BK, arow0, MROWS - 1, As1, w, l);
    stage128(Wt + (kt + 1) * BK, brow0, NCAT - 1, Bs1, w, l);
    compute128(As0, Bs0, wr, wc, li, lg, acc);
    __syncthreads();
    if (kt2 < 5) {
      stage128(Xb + (kt + 2) * BK, arow0, MROWS - 1, As0, w, l);
      stage128(Wt + (kt + 2) * BK, brow0, NCAT - 1, Bs0, w, l);
    }
    compute128(As1, Bs1, wr, wc, li, lg, acc);
    __syncthreads();                        // also frees LDSU for the V epilogue
  }

  const int mblk = nt / 6;                 // 0=Q, 1=K, 2=V (block-uniform)
  float bcv[4];
#pragma unroll
  for (int ni = 0; ni < 4; ++ni) bcv[ni] = bc[brow0 + wc * 64 + ni * 16 + li];

  if (mblk < 2) {
    u16* __restrict__ dst = (mblk == 0) ? Qw : Kw;
    const float scale = (mblk == 0) ? 0.125f : 1.0f;
    int hv[4], dv[4];
#pragma unroll
    for (int ni = 0; ni < 4; ++ni) {
      int cloc = brow0 - mblk * HID + wc * 64 + ni * 16 + li;
      hv[ni] = cloc >> 6; dv[ni] = cloc & 63;
    }
#pragma unroll
    for (int mi = 0; mi < 4; ++mi) {
#pragma unroll
      for (int j = 0; j < 4; ++j) {
        int row = arow0 + wr * 64 + mi * 16 + lg * 4 + j;
        if (row < MROWS) {
          int b = row / SEQ, s = row - b * SEQ;
#pragma unroll
          for (int ni = 0; ni < 4; ++ni)
            dst[((size_t)(b * NH + hv[ni]) * SEQ + s) * DH + dv[ni]] = f2bf((acc[mi][ni][j] + bcv[ni]) * scale);
        }
      }
    }
  } else {
    // V: transpose via reused LDS (stride-68 pad), store s-contiguous
#pragma unroll
    for (int mi = 0; mi < 4; ++mi) {
#pragma unroll
      for (int ni = 0; ni < 4; ++ni) {
        u16x4 pk;
#pragma unroll
        for (int j = 0; j < 4; ++j) pk[j] = f2bf(acc[mi][ni][j] + bcv[ni]);
        *(u16x4*)&LDSU[w * 4352 + (ni * 16 + li) * 68 + mi * 16 + lg * 4] = pk;
      }
    }
    __syncthreads();
    const int cw0 = brow0 - 2 * HID;       // V-local col base (2 heads per tile)
#pragma unroll 4
    for (int p = 0; p < 64; ++p) {
      int i = p * 256 + tid;
      int r = i & 127, c = i >> 7;         // lane-consecutive r -> coalesced store
      int wq = ((r >> 6) << 1) | (c >> 6);
      u16 v = LDSU[wq * 4352 + (c & 63) * 68 + (r & 63)];
      int row = arow0 + r;
      if (row < MROWS) {
        int b = row / SEQ, s = row - b * SEQ;
        int cl = cw0 + c;
        int h = cl >> 6, d = cl & 63;
        Vt[((size_t)(b * NH + h) * DH + d) * VP + s] = v;
      }
    }
  }
}

// ---------------- fused attention: 1 BLOCK per bh (2 waves), K AND V staged in LDS ----------------
// r18 retry with the conflict cause fixed: V LDS rows use P's proven 232-u16
// (464B) stride — 464B = 20 dwords mod 32 walks successive rows across all 8
// bank-quads (vs r18's 512B = 0 mod 128B that caused 8-way conflicts). Linear
// chunk staging (no swizzle); pad cols 224..231 never read (t<=6 caps at 224).
// LDS 71.2 KB -> 2 blocks/CU; the L2 latency chain this TLP hid is removed.
__global__ __launch_bounds__(128, 2) void attn(const u16* __restrict__ Qw, const u16* __restrict__ Kw,
                                               const u16* __restrict__ Vt, const u16* __restrict__ Bxt,
                                               float* __restrict__ out) {
  __shared__ u16 Klds[208 * 64];   // 16B chunk (r,c) holds K[r][(c^(r&7))*8 ..]
  __shared__ u16 Vlds[64 * 232];   // row d at d*232; cols 0..223 = Vt[d][s], 224..231 pad
  __shared__ u16 P[2][16 * 232];   // per-wave P transpose buffer
  const int tid = threadIdx.x;
  const int w = tid >> 6, l = tid & 63;
  const int lg = l >> 4, li = l & 15;
  const int lin = blockIdx.x;
  const int bh = (lin & 7) * 96 + (lin >> 3);   // 768 = 8*96 bijective XCD chunking
  const int b = bh / NH, h = bh - b * NH;

  const u16* Qb = Qw + (size_t)bh * QKSTRIDE;
  const u16* Kb = Kw + (size_t)bh * QKSTRIDE;
  const u16* Vb = Vt + (size_t)bh * DH * VP;

  // ---- stage K into LDS: 1664 16B chunks, wave w covers groups w*13..w*13+12 ----
#pragma unroll
  for (int i = 0; i < 13; ++i) {
    int ch = (w * 13 + i) * 64 + l;            // 0..1663
    int r = ch >> 3, c = ch & 7;
    int sc = c ^ (r & 7);                      // inverse swizzle on source
    __builtin_amdgcn_global_load_lds((const __attribute__((address_space(1))) void*)
                                         (Kb + (size_t)r * DH + sc * 8),
                                     (__attribute__((address_space(3))) void*)(Klds + (size_t)ch * 8),
                                     16, 0, 0);
  }
  // ---- stage V into LDS: 64 rows x 29 chunks = 1856 chunks, linear (no swizzle) ----
  // chunk ch = r*29 + c; c<28 -> data Vt[r][c*8..], c==28 -> pad (dummy source, never read)
#pragma unroll
  for (int i = 0; i < 15; ++i) {
    int ch = i * 128 + tid;                    // 0..1919
    if (ch < 1856) {
      int r = ch / 29, c = ch - r * 29;
      const u16* src = (c < 28) ? (Vb + (size_t)r * VP + c * 8) : Vb;
      __builtin_amdgcn_global_load_lds((const __attribute__((address_space(1))) void*)src,
                                       (__attribute__((address_space(3))) void*)(Vlds + (size_t)ch * 8),
                                       16, 0, 0);
    }
  }
  // zero P tail cols 208..231 for this wave
  for (int t = l; t < 16 * 24; t += 64) {
    int rr = t / 24, cc = t - rr * 24;
    P[w][rr * 232 + 208 + cc] = 0;
  }
  __syncthreads();                             // K,V visible to both waves

  for (int it = 0; it < 7; ++it) {
    const int qf = w + 2 * it;                 // w0: 0,2,..,12 ; w1: 1,3,..,11
    if (qf >= 13) break;                       // wave-uniform

    const u16x4* Bht = (const u16x4*)Bxt + ((size_t)(h * 13 + qf) * 13) * 64 + l;

    // Q frags (rows may over-read into pad: finite, outputs guarded)
    s16x8 a0 = *(const s16x8*)(Qb + (size_t)(qf * 16 + li) * DH + lg * 8);
    s16x8 a1 = *(const s16x8*)(Qb + (size_t)(qf * 16 + li) * DH + 32 + lg * 8);

    // batched bias loads — tiled layout: one coalesced 512B segment per kf
    u16x4 bb[13];
#pragma unroll
    for (int kf = 0; kf < 13; ++kf)
      bb[kf] = Bht[kf * 64];

    // QK^T with K frags from LDS (swizzled, conflict-free)
    f32x4 S[13];
#pragma unroll
    for (int kf = 0; kf < 13; ++kf) {
      int r = kf * 16 + li;
      s16x8 k0 = *(const s16x8*)((const char*)Klds + r * 128 + ((lg) ^ (r & 7)) * 16);
      s16x8 k1 = *(const s16x8*)((const char*)Klds + r * 128 + ((4 + lg) ^ (r & 7)) * 16);
      f32x4 c = {};
      c = __builtin_amdgcn_mfma_f32_16x16x32_bf16(a0, k0, c, 0, 0, 0);
      c = __builtin_amdgcn_mfma_f32_16x16x32_bf16(a1, k1, c, 0, 0, 0);
#pragma unroll
      for (int j = 0; j < 4; ++j)
        S[kf][j] = c[j] + bf2f(bb[kf][j]);
    }

    // softmax over 13 regs x 16 lanes (per 16-lane group)
    float rinv[4];
#pragma unroll
    for (int j = 0; j < 4; ++j) {
      float m = S[0][j];
#pragma unroll
      for (int kf = 1; kf < 13; ++kf) m = fmaxf(m, S[kf][j]);
      m = fmaxf(m, __shfl_xor(m, 1));
      m = fmaxf(m, __shfl_xor(m, 2));
      m = fmaxf(m, __shfl_xor(m, 4));
      m = fmaxf(m, __shfl_xor(m, 8));
      float sum = 0.f;
#pragma unroll
      for (int kf = 0; kf < 13; ++kf) {
        float p = __expf(S[kf][j] - m);
        S[kf][j] = p;
        sum += p;
      }
      sum += __shfl_xor(sum, 1);
      sum += __shfl_xor(sum, 2);
      sum += __shfl_xor(sum, 4);
      sum += __shfl_xor(sum, 8);
      rinv[j] = 1.0f / sum;
    }

    // transpose P into this wave's LDS buffer (bf16)
#pragma unroll
    for (int kf = 0; kf < 13; ++kf)
#pragma unroll
      for (int j = 0; j < 4; ++j)
        P[w][(lg * 4 + j) * 232 + kf * 16 + li] = f2bf(S[kf][j]);

    // PV with V frags from LDS (232-stride rows, P-like mild-conflict layout)
    f32x4 o[4];
#pragma unroll
    for (int nf = 0; nf < 4; ++nf) {
      f32x4 c = {};
      const int r = nf * 16 + li;
#pragma unroll
      for (int t = 0; t < 7; ++t) {
        s16x8 pa = *(const s16x8*)(&P[w][li * 232 + t * 32 + lg * 8]);
        s16x8 vb = *(const s16x8*)(&Vlds[r * 232 + t * 32 + lg * 8]);
        c = __builtin_amdgcn_mfma_f32_16x16x32_bf16(pa, vb, c, 0, 0, 0);
      }
      o[nf] = c;
    }
#pragma unroll
    for (int nf = 0; nf < 4; ++nf) {
#pragma unroll
      for (int j = 0; j < 4; ++j) {
        int q = qf * 16 + lg * 4 + j;
        if (q < SEQ)
          out[((size_t)(b * SEQ + q)) * HID + h * DH + nf * 16 + li] = o[nf][j] * rinv[j];
      }
    }
  }
}

extern "C" void kernel_launch(void* const* d_in, const int* in_sizes, int n_in,
                              void* d_out, int out_size, void* d_ws, size_t ws_size,
                              hipStream_t stream) {
  const float* hidden = (const float*)d_in[0];
  const float* Wq = (const float*)d_in[1];
  const float* bq = (const float*)d_in[2];
  const float* Wk = (const float*)d_in[3];
  const float* Wv = (const float*)d_in[4];
  const float* bv = (const float*)d_in[5];
  const float* btab = (const float*)d_in[6];
  float* out = (float*)d_out;

  // workspace layout (peak 84,712,576 B, within proven budget):
  char* ws = (char*)d_ws;
  u16* Xb  = (u16*)(ws);                       // [0, 19,365,888)   12608*768*2
  u16* Wt  = (u16*)(ws + 19365888);            // [.., 22,904,832)  2304*768*2
  float* bc = (float*)(ws + 22904832);         // [.., 22,914,048)  2304*4
  u16* Bxt = (u16*)(ws + 22914048);            // [.., 23,952,384)  12*13*13*64*4 u16 = 1,038,336 B
  u16* Qw  = (u16*)(ws + 23952512);            // [.., 43,322,496)  (768*197+32)*64*2
  u16* Kw  = (u16*)(ws + 43322496);            // [.., 62,692,480)  (768*197+32)*64*2
  u16* Vt  = (u16*)(ws + 62692480);            // [.., 84,712,576)  768*64*224*2

  prep_all<<<dim3(PB_E), dim3(256), 0, stream>>>(hidden, Wq, Wk, Wv, bq, bv, btab, Xb, Wt, bc, Bxt);
  qkv_gemm<<<dim3(NWG), dim3(256), 0, stream>>>(Xb, Wt, bc, Qw, Kw, Vt);
  attn<<<dim3(768), dim3(128), 0, stream>>>(Qw, Kw, Vt, Bxt, out);
}

// Round 21
// 114.066 us; speedup vs baseline: 1.1835x; 1.1835x over previous
//
#include <hip/hip_runtime.h>
#include <hip/hip_bf16.h>
#include <stdint.h>

typedef unsigned short u16;
typedef __attribute__((ext_vector_type(4))) float f32x4;
typedef __attribute__((ext_vector_type(8))) short s16x8;
typedef __attribute__((ext_vector_type(4))) unsigned short u16x4;
typedef __attribute__((ext_vector_type(4))) float fvec4;

#define NH 12
#define DH 64
#define HID 768
#define SEQ 197
#define VP 224            // padded seq cols for Vt slab (global)
#define NREL 732
#define BATCH 64
#define MROWS (BATCH*SEQ) // 12608
#define NCAT (3*HID)      // 2304
#define BK 64
#define MT 99             // grid tiles in M (99*128 = 12672 >= 12608)
#define NT 18             // grid tiles in N (18*128 = 2304)
#define NWG (MT*NT)       // 1782
#define QKSTRIDE (SEQ*DH) // 12608 u16 per bh slab (tight)

// prep_all block ranges
#define PB_X 4728                 // conv_x: 4728*256*8 = 12608*768
#define PB_W (PB_X + 432)         // conv_w: 36*12 tiles
#define PB_B (PB_W + 9)           // conv_b
#define PB_E (PB_B + 507)         // bias tiles: 12*13*13*64 = 129,792 = 507*256 exact

static __device__ __forceinline__ u16 f2bf(float f) {
  union { float f; uint32_t u; } v; v.f = f;
  uint32_t u = v.u;
  return (u16)((u + 0x7FFFu + ((u >> 16) & 1u)) >> 16);
}
static __device__ __forceinline__ float bf2f(u16 v) {
  union { uint32_t u; float f; } x; x.u = ((uint32_t)v) << 16; return x.f;
}

// ---------------- fused prep: conv_x | conv_w | conv_b | expand_bias(tiled) ----------------
__global__ __launch_bounds__(256) void prep_all(const float* __restrict__ x,
                                                const float* __restrict__ Wq, const float* __restrict__ Wk,
                                                const float* __restrict__ Wv, const float* __restrict__ bq,
                                                const float* __restrict__ bv, const float* __restrict__ btab,
                                                u16* __restrict__ xb, u16* __restrict__ Wt,
                                                float* __restrict__ bc, u16* __restrict__ Bxt) {
  __shared__ float t[64][65];
  const int bi = blockIdx.x;
  const int tid = threadIdx.x;
  if (bi < PB_X) {
    // hidden fp32 -> bf16, 8 elems/thread
    int i = bi * 256 + tid;
    fvec4 a = ((const fvec4*)x)[2 * i];
    fvec4 b = ((const fvec4*)x)[2 * i + 1];
    s16x8 r;
    r[0] = (short)f2bf(a[0]); r[1] = (short)f2bf(a[1]); r[2] = (short)f2bf(a[2]); r[3] = (short)f2bf(a[3]);
    r[4] = (short)f2bf(b[0]); r[5] = (short)f2bf(b[1]); r[6] = (short)f2bf(b[2]); r[7] = (short)f2bf(b[3]);
    ((s16x8*)xb)[i] = r;
  } else if (bi < PB_W) {
    // W's -> transposed concat bf16 [NCAT][HID]
    int f = bi - PB_X;
    int n0 = (f % 36) * 64, k0 = (f / 36) * 64;
    int m = n0 / HID;
    const float* W = (m == 0) ? Wq : ((m == 1) ? Wk : Wv);
    int nn0 = n0 - m * HID;
    for (int i = tid; i < 64 * 64; i += 256) {
      int r = i >> 6, c = i & 63;
      t[r][c] = W[(size_t)(k0 + r) * HID + nn0 + c];
    }
    __syncthreads();
    for (int i = tid; i < 64 * 64; i += 256) {
      int r = i >> 6, c = i & 63;
      Wt[(size_t)(n0 + r) * HID + k0 + c] = f2bf(t[c][r]);
    }
  } else if (bi < PB_B) {
    int i = (bi - PB_W) * 256 + tid;
    if (i < NCAT) {
      int m = i / HID, r = i - m * HID;
      bc[i] = (m == 0) ? bq[r] : ((m == 2) ? bv[r] : 0.f);
    }
  } else {
    // bias tiles: entry (h, qf, kf, lane) -> u16x4 of bias(q = qf*16+lg*4+j, k = kf*16+li)
    int i = (bi - PB_B) * 256 + tid;       // < 129,792 exact
    int h = i / (13 * 13 * 64);
    int rem = i - h * (13 * 13 * 64);
    int qf = rem / (13 * 64);
    int rem2 = rem - qf * (13 * 64);
    int kf = rem2 >> 6, lane = rem2 & 63;
    int li = lane & 15, lg = lane >> 4;
    int k = kf * 16 + li;
    u16x4 outv;
#pragma unroll
    for (int j = 0; j < 4; ++j) {
      int q = qf * 16 + lg * 4 + j;
      float v;
      if (k >= SEQ) v = -1e30f;            // mask padded k (incl. cross-slab garbage)
      else if (q >= SEQ) v = 0.f;          // padded q rows: outputs discarded
      else {
        int idx;
        if (q == 0) idx = (k == 0) ? 731 : 729;
        else if (k == 0) idx = 730;
        else {
          int iq = (q - 1) / 14, jq = (q - 1) % 14;
          int ik = (k - 1) / 14, jk = (k - 1) % 14;
          idx = (iq - ik + 13) * 27 + (jq - jk + 13);
        }
        v = btab[(size_t)idx * NH + h];
      }
      outv[j] = f2bf(v);
    }
    ((u16x4*)Bxt)[i] = outv;
  }
}

// ---------------- fused QKV GEMM (r12/r15-proven: ~73 us, fused V-transpose epilogue) ----------------
static __device__ __forceinline__ void stage128(const u16* __restrict__ gbase, int grow0, int growmax,
                                                u16* lds, int w, int l) {
#pragma unroll
  for (int i = 0; i < 4; ++i) {
    int ch = w * 4 + i;                    // wave-uniform 0..15
    int r = ch * 8 + (l >> 3);
    int grow = grow0 + r; if (grow > growmax) grow = growmax;
    int c = (l & 7) ^ (l >> 3);            // inverse swizzle on source
    const u16* g = gbase + (size_t)grow * HID + c * 8;
    __builtin_amdgcn_global_load_lds((const __attribute__((address_space(1))) void*)g,
                                     (__attribute__((address_space(3))) void*)(lds + ch * 512),
                                     16, 0, 0);
  }
}

static __device__ __forceinline__ void compute128(const u16* As, const u16* Bs, int wr, int wc,
                                                  int li, int lg, f32x4 acc[4][4]) {
#pragma unroll
  for (int kk = 0; kk < 2; ++kk) {
    s16x8 af[4], bf[4];
#pragma unroll
    for (int mi = 0; mi < 4; ++mi) {
      int r = wr * 64 + mi * 16 + li;
      int c = (kk * 4 + lg) ^ (r & 7);
      af[mi] = *(const s16x8*)((const char*)As + r * 128 + c * 16);
    }
#pragma unroll
    for (int ni = 0; ni < 4; ++ni) {
      int r = wc * 64 + ni * 16 + li;
      int c = (kk * 4 + lg) ^ (r & 7);
      bf[ni] = *(const s16x8*)((const char*)Bs + r * 128 + c * 16);
    }
#pragma unroll
    for (int mi = 0; mi < 4; ++mi)
#pragma unroll
      for (int ni = 0; ni < 4; ++ni)
        acc[mi][ni] = __builtin_amdgcn_mfma_f32_16x16x32_bf16(af[mi], bf[ni], acc[mi][ni], 0, 0, 0);
  }
}

__global__ __launch_bounds__(256, 2) void qkv_gemm(const u16* __restrict__ Xb, const u16* __restrict__ Wt,
                                                   const float* __restrict__ bc, u16* __restrict__ Qw,
                                                   u16* __restrict__ Kw, u16* __restrict__ Vt) {
  __shared__ u16 LDSU[32768];               // 64 KiB union: staging buffers / V-transpose
  u16* As0 = LDSU;
  u16* Bs0 = LDSU + 8192;
  u16* As1 = LDSU + 16384;
  u16* Bs1 = LDSU + 24576;
  const int tid = threadIdx.x;
  const int w = tid >> 6, l = tid & 63;
  const int wr = w >> 1, wc = w & 1;        // 2x2 wave grid, 64x64 per wave
  const int lg = l >> 4, li = l & 15;

  // bijective XCD chunking (m204): nwg=1782, q=222, r=6
  const int lin = blockIdx.x;
  const int xcd = lin & 7;
  const int pos = lin >> 3;
  const int work = (xcd < 6 ? xcd * 223 : 6 * 223 + (xcd - 6) * 222) + pos;
  const int mt = work / NT, nt = work - mt * NT;
  const int arow0 = mt * 128, brow0 = nt * 128;

  f32x4 acc[4][4] = {};

  stage128(Xb, arow0, MROWS - 1, As0, w, l);
  stage128(Wt, brow0, NCAT - 1, Bs0, w, l);
  __syncthreads();

  for (int kt2 = 0; kt2 < 6; ++kt2) {
    const int kt = kt2 * 2;
    stage128(Xb + (kt + 1) * BK, arow0, MROWS - 1, As1, w, l);
    stage128(Wt + (kt + 1) * BK, brow0, NCAT - 1, Bs1, w, l);
    compute128(As0, Bs0, wr, wc, li, lg, acc);
    __syncthreads();
    if (kt2 < 5) {
      stage128(Xb + (kt + 2) * BK, arow0, MROWS - 1, As0, w, l);
      stage128(Wt + (kt + 2) * BK, brow0, NCAT - 1, Bs0, w, l);
    }
    compute128(As1, Bs1, wr, wc, li, lg, acc);
    __syncthreads();                        // also frees LDSU for the V epilogue
  }

  const int mblk = nt / 6;                 // 0=Q, 1=K, 2=V (block-uniform)
  float bcv[4];
#pragma unroll
  for (int ni = 0; ni < 4; ++ni) bcv[ni] = bc[brow0 + wc * 64 + ni * 16 + li];

  if (mblk < 2) {
    u16* __restrict__ dst = (mblk == 0) ? Qw : Kw;
    const float scale = (mblk == 0) ? 0.125f : 1.0f;
    int hv[4], dv[4];
#pragma unroll
    for (int ni = 0; ni < 4; ++ni) {
      int cloc = brow0 - mblk * HID + wc * 64 + ni * 16 + li;
      hv[ni] = cloc >> 6; dv[ni] = cloc & 63;
    }
#pragma unroll
    for (int mi = 0; mi < 4; ++mi) {
#pragma unroll
      for (int j = 0; j < 4; ++j) {
        int row = arow0 + wr * 64 + mi * 16 + lg * 4 + j;
        if (row < MROWS) {
          int b = row / SEQ, s = row - b * SEQ;
#pragma unroll
          for (int ni = 0; ni < 4; ++ni)
            dst[((size_t)(b * NH + hv[ni]) * SEQ + s) * DH + dv[ni]] = f2bf((acc[mi][ni][j] + bcv[ni]) * scale);
        }
      }
    }
  } else {
    // V: transpose via reused LDS (stride-68 pad), store s-contiguous
#pragma unroll
    for (int mi = 0; mi < 4; ++mi) {
#pragma unroll
      for (int ni = 0; ni < 4; ++ni) {
        u16x4 pk;
#pragma unroll
        for (int j = 0; j < 4; ++j) pk[j] = f2bf(acc[mi][ni][j] + bcv[ni]);
        *(u16x4*)&LDSU[w * 4352 + (ni * 16 + li) * 68 + mi * 16 + lg * 4] = pk;
      }
    }
    __syncthreads();
    const int cw0 = brow0 - 2 * HID;       // V-local col base (2 heads per tile)
#pragma unroll 4
    for (int p = 0; p < 64; ++p) {
      int i = p * 256 + tid;
      int r = i & 127, c = i >> 7;         // lane-consecutive r -> coalesced store
      int wq = ((r >> 6) << 1) | (c >> 6);
      u16 v = LDSU[wq * 4352 + (c & 63) * 68 + (r & 63)];
      int row = arow0 + r;
      if (row < MROWS) {
        int b = row / SEQ, s = row - b * SEQ;
        int cl = cw0 + c;
        int h = cl >> 6, d = cl & 63;
        Vt[((size_t)(b * NH + h) * DH + d) * VP + s] = v;
      }
    }
  }
}

// ---------------- fused attention: 1 BLOCK per bh (2 waves), K staged in LDS (r19-proven) ----------------
// LDS 41.4 KB -> 3 blocks/CU; 768 blocks = 3*256 EXACT (zero dispatch tail; the
// r18/r20 V-in-LDS variants broke this fit and regressed). V latency hidden by
// an 8-deep register pipeline instead.
__global__ __launch_bounds__(128, 2) void attn(const u16* __restrict__ Qw, const u16* __restrict__ Kw,
                                               const u16* __restrict__ Vt, const u16* __restrict__ Bxt,
                                               float* __restrict__ out) {
  __shared__ u16 Klds[208 * 64];   // LDS 16B-chunk (r,c) holds K[r][ (c^(r&7))*8 .. +7 ]
  __shared__ u16 P[2][16 * 232];   // per-wave P transpose buffer
  const int tid = threadIdx.x;
  const int w = tid >> 6, l = tid & 63;
  const int lg = l >> 4, li = l & 15;
  const int lin = blockIdx.x;
  const int bh = (lin & 7) * 96 + (lin >> 3);   // 768 = 8*96 bijective XCD chunking
  const int b = bh / NH, h = bh - b * NH;

  const u16* Qb = Qw + (size_t)bh * QKSTRIDE;
  const u16* Kb = Kw + (size_t)bh * QKSTRIDE;
  const u16* Vb = Vt + (size_t)bh * DH * VP;

  // ---- stage K into LDS: 1664 16B chunks, wave w covers groups w*13..w*13+12 ----
#pragma unroll
  for (int i = 0; i < 13; ++i) {
    int ch = (w * 13 + i) * 64 + l;            // 0..1663
    int r = ch >> 3, c = ch & 7;
    int sc = c ^ (r & 7);                      // inverse swizzle on source
    __builtin_amdgcn_global_load_lds((const __attribute__((address_space(1))) void*)
                                         (Kb + (size_t)r * DH + sc * 8),
                                     (__attribute__((address_space(3))) void*)(Klds + (size_t)ch * 8),
                                     16, 0, 0);
  }
  // zero P tail cols 208..231 for this wave
  for (int t = l; t < 16 * 24; t += 64) {
    int rr = t / 24, cc = t - rr * 24;
    P[w][rr * 232 + 208 + cc] = 0;
  }
  __syncthreads();                             // K visible to both waves

  for (int it = 0; it < 7; ++it) {
    const int qf = w + 2 * it;                 // w0: 0,2,..,12 ; w1: 1,3,..,11
    if (qf >= 13) break;                       // wave-uniform

    const u16x4* Bht = (const u16x4*)Bxt + ((size_t)(h * 13 + qf) * 13) * 64 + l;

    // Q frags (rows may over-read into pad: finite, outputs guarded)
    s16x8 a0 = *(const s16x8*)(Qb + (size_t)(qf * 16 + li) * DH + lg * 8);
    s16x8 a1 = *(const s16x8*)(Qb + (size_t)(qf * 16 + li) * DH + 32 + lg * 8);

    // batched bias loads — tiled layout: one coalesced 512B segment per kf
    u16x4 bb[13];
#pragma unroll
    for (int kf = 0; kf < 13; ++kf)
      bb[kf] = Bht[kf * 64];

    // QK^T with K frags from LDS (swizzled, conflict-free)
    f32x4 S[13];
#pragma unroll
    for (int kf = 0; kf < 13; ++kf) {
      int r = kf * 16 + li;
      s16x8 k0 = *(const s16x8*)((const char*)Klds + r * 128 + ((lg) ^ (r & 7)) * 16);
      s16x8 k1 = *(const s16x8*)((const char*)Klds + r * 128 + ((4 + lg) ^ (r & 7)) * 16);
      f32x4 c = {};
      c = __builtin_amdgcn_mfma_f32_16x16x32_bf16(a0, k0, c, 0, 0, 0);
      c = __builtin_amdgcn_mfma_f32_16x16x32_bf16(a1, k1, c, 0, 0, 0);
#pragma unroll
      for (int j = 0; j < 4; ++j)
        S[kf][j] = c[j] + bf2f(bb[kf][j]);
    }

    // softmax over 13 regs x 16 lanes (per 16-lane group)
    float rinv[4];
#pragma unroll
    for (int j = 0; j < 4; ++j) {
      float m = S[0][j];
#pragma unroll
      for (int kf = 1; kf < 13; ++kf) m = fmaxf(m, S[kf][j]);
      m = fmaxf(m, __shfl_xor(m, 1));
      m = fmaxf(m, __shfl_xor(m, 2));
      m = fmaxf(m, __shfl_xor(m, 4));
      m = fmaxf(m, __shfl_xor(m, 8));
      float sum = 0.f;
#pragma unroll
      for (int kf = 0; kf < 13; ++kf) {
        float p = __expf(S[kf][j] - m);
        S[kf][j] = p;
        sum += p;
      }
      sum += __shfl_xor(sum, 1);
      sum += __shfl_xor(sum, 2);
      sum += __shfl_xor(sum, 4);
      sum += __shfl_xor(sum, 8);
      rinv[j] = 1.0f / sum;
    }

    // transpose P into this wave's LDS buffer (bf16)
#pragma unroll
    for (int kf = 0; kf < 13; ++kf)
#pragma unroll
      for (int j = 0; j < 4; ++j)
        P[w][(lg * 4 + j) * 232 + kf * 16 + li] = f2bf(S[kf][j]);

    // PV with 8-deep V-frag pipeline (V from global/L2; flat u = nf*7+t)
    s16x8 vb[8];
#pragma unroll
    for (int p = 0; p < 8; ++p)
      vb[p] = *(const s16x8*)(Vb + (size_t)((p / 7) * 16 + li) * VP + (p % 7) * 32 + lg * 8);
    f32x4 o[4];
#pragma unroll
    for (int nf = 0; nf < 4; ++nf) {
      f32x4 c = {};
#pragma unroll
      for (int t = 0; t < 7; ++t) {
        const int u = nf * 7 + t, slot = u & 7;   // static (fully unrolled)
        s16x8 pa = *(const s16x8*)(&P[w][li * 232 + t * 32 + lg * 8]);
        c = __builtin_amdgcn_mfma_f32_16x16x32_bf16(pa, vb[slot], c, 0, 0, 0);
        if (u + 8 < 28) {
          const int u2 = u + 8;
          vb[slot] = *(const s16x8*)(Vb + (size_t)((u2 / 7) * 16 + li) * VP + (u2 % 7) * 32 + lg * 8);
        }
      }
      o[nf] = c;
    }
#pragma unroll
    for (int nf = 0; nf < 4; ++nf) {
#pragma unroll
      for (int j = 0; j < 4; ++j) {
        int q = qf * 16 + lg * 4 + j;
        if (q < SEQ)
          out[((size_t)(b * SEQ + q)) * HID + h * DH + nf * 16 + li] = o[nf][j] * rinv[j];
      }
    }
  }
}

extern "C" void kernel_launch(void* const* d_in, const int* in_sizes, int n_in,
                              void* d_out, int out_size, void* d_ws, size_t ws_size,
                              hipStream_t stream) {
  const float* hidden = (const float*)d_in[0];
  const float* Wq = (const float*)d_in[1];
  const float* bq = (const float*)d_in[2];
  const float* Wk = (const float*)d_in[3];
  const float* Wv = (const float*)d_in[4];
  const float* bv = (const float*)d_in[5];
  const float* btab = (const float*)d_in[6];
  float* out = (float*)d_out;

  // workspace layout (peak 84,712,576 B, within proven budget):
  char* ws = (char*)d_ws;
  u16* Xb  = (u16*)(ws);                       // [0, 19,365,888)   12608*768*2
  u16* Wt  = (u16*)(ws + 19365888);            // [.., 22,904,832)  2304*768*2
  float* bc = (float*)(ws + 22904832);         // [.., 22,914,048)  2304*4
  u16* Bxt = (u16*)(ws + 22914048);            // [.., 23,952,384)  12*13*13*64*4 u16 = 1,038,336 B
  u16* Qw  = (u16*)(ws + 23952512);            // [.., 43,322,496)  (768*197+32)*64*2
  u16* Kw  = (u16*)(ws + 43322496);            // [.., 62,692,480)  (768*197+32)*64*2
  u16* Vt  = (u16*)(ws + 62692480);            // [.., 84,712,576)  768*64*224*2

  prep_all<<<dim3(PB_E), dim3(256), 0, stream>>>(hidden, Wq, Wk, Wv, bq, bv, btab, Xb, Wt, bc, Bxt);
  qkv_gemm<<<dim3(NWG), dim3(256), 0, stream>>>(Xb, Wt, bc, Qw, Kw, Vt);
  attn<<<dim3(768), dim3(128), 0, stream>>>(Qw, Kw, Vt, Bxt, out);
}

// Round 22
// 113.556 us; speedup vs baseline: 1.1888x; 1.0045x over previous
//
#include <hip/hip_runtime.h>
#include <hip/hip_bf16.h>
#include <stdint.h>

typedef unsigned short u16;
typedef __attribute__((ext_vector_type(4))) float f32x4;
typedef __attribute__((ext_vector_type(8))) short s16x8;
typedef __attribute__((ext_vector_type(4))) unsigned short u16x4;
typedef __attribute__((ext_vector_type(4))) float fvec4;

#define NH 12
#define DH 64
#define HID 768
#define SEQ 197
#define VP 224            // padded seq cols for Vt slab (global)
#define NREL 732
#define BATCH 64
#define MROWS (BATCH*SEQ) // 12608
#define NCAT (3*HID)      // 2304
#define BK 64
#define MT 99             // grid tiles in M (99*128 = 12672 >= 12608)
#define NT 18             // grid tiles in N (18*128 = 2304)
#define NWG (MT*NT)       // 1782
#define QKSTRIDE (SEQ*DH) // 12608 u16 per bh slab (tight)

// prep_all block ranges
#define PB_X 4728                 // conv_x: 4728*256*8 = 12608*768
#define PB_W (PB_X + 432)         // conv_w: 36*12 tiles
#define PB_B (PB_W + 9)           // conv_b
#define PB_E (PB_B + 507)         // bias tiles: 12*13*13*64 = 129,792 = 507*256 exact

static __device__ __forceinline__ u16 f2bf(float f) {
  union { float f; uint32_t u; } v; v.f = f;
  uint32_t u = v.u;
  return (u16)((u + 0x7FFFu + ((u >> 16) & 1u)) >> 16);
}
static __device__ __forceinline__ float bf2f(u16 v) {
  union { uint32_t u; float f; } x; x.u = ((uint32_t)v) << 16; return x.f;
}

// ---------------- fused prep: conv_x | conv_w | conv_b | expand_bias(tiled) ----------------
__global__ __launch_bounds__(256) void prep_all(const float* __restrict__ x,
                                                const float* __restrict__ Wq, const float* __restrict__ Wk,
                                                const float* __restrict__ Wv, const float* __restrict__ bq,
                                                const float* __restrict__ bv, const float* __restrict__ btab,
                                                u16* __restrict__ xb, u16* __restrict__ Wt,
                                                float* __restrict__ bc, u16* __restrict__ Bxt) {
  __shared__ float t[64][65];
  const int bi = blockIdx.x;
  const int tid = threadIdx.x;
  if (bi < PB_X) {
    // hidden fp32 -> bf16, 8 elems/thread
    int i = bi * 256 + tid;
    fvec4 a = ((const fvec4*)x)[2 * i];
    fvec4 b = ((const fvec4*)x)[2 * i + 1];
    s16x8 r;
    r[0] = (short)f2bf(a[0]); r[1] = (short)f2bf(a[1]); r[2] = (short)f2bf(a[2]); r[3] = (short)f2bf(a[3]);
    r[4] = (short)f2bf(b[0]); r[5] = (short)f2bf(b[1]); r[6] = (short)f2bf(b[2]); r[7] = (short)f2bf(b[3]);
    ((s16x8*)xb)[i] = r;
  } else if (bi < PB_W) {
    // W's -> transposed concat bf16 [NCAT][HID]
    int f = bi - PB_X;
    int n0 = (f % 36) * 64, k0 = (f / 36) * 64;
    int m = n0 / HID;
    const float* W = (m == 0) ? Wq : ((m == 1) ? Wk : Wv);
    int nn0 = n0 - m * HID;
    for (int i = tid; i < 64 * 64; i += 256) {
      int r = i >> 6, c = i & 63;
      t[r][c] = W[(size_t)(k0 + r) * HID + nn0 + c];
    }
    __syncthreads();
    for (int i = tid; i < 64 * 64; i += 256) {
      int r = i >> 6, c = i & 63;
      Wt[(size_t)(n0 + r) * HID + k0 + c] = f2bf(t[c][r]);
    }
  } else if (bi < PB_B) {
    int i = (bi - PB_W) * 256 + tid;
    if (i < NCAT) {
      int m = i / HID, r = i - m * HID;
      bc[i] = (m == 0) ? bq[r] : ((m == 2) ? bv[r] : 0.f);
    }
  } else {
    // bias tiles: entry (h, qf, kf, lane) -> u16x4 of bias(q = qf*16+lg*4+j, k = kf*16+li)
    int i = (bi - PB_B) * 256 + tid;       // < 129,792 exact
    int h = i / (13 * 13 * 64);
    int rem = i - h * (13 * 13 * 64);
    int qf = rem / (13 * 64);
    int rem2 = rem - qf * (13 * 64);
    int kf = rem2 >> 6, lane = rem2 & 63;
    int li = lane & 15, lg = lane >> 4;
    int k = kf * 16 + li;
    u16x4 outv;
#pragma unroll
    for (int j = 0; j < 4; ++j) {
      int q = qf * 16 + lg * 4 + j;
      float v;
      if (k >= SEQ) v = -1e30f;            // mask padded k (incl. cross-slab garbage)
      else if (q >= SEQ) v = 0.f;          // padded q rows: outputs discarded
      else {
        int idx;
        if (q == 0) idx = (k == 0) ? 731 : 729;
        else if (k == 0) idx = 730;
        else {
          int iq = (q - 1) / 14, jq = (q - 1) % 14;
          int ik = (k - 1) / 14, jk = (k - 1) % 14;
          idx = (iq - ik + 13) * 27 + (jq - jk + 13);
        }
        v = btab[(size_t)idx * NH + h];
      }
      outv[j] = f2bf(v);
    }
    ((u16x4*)Bxt)[i] = outv;
  }
}

// ---------------- fused QKV GEMM (r12/r15-proven: ~73 us, fused V-transpose epilogue) ----------------
static __device__ __forceinline__ void stage128(const u16* __restrict__ gbase, int grow0, int growmax,
                                                u16* lds, int w, int l) {
#pragma unroll
  for (int i = 0; i < 4; ++i) {
    int ch = w * 4 + i;                    // wave-uniform 0..15
    int r = ch * 8 + (l >> 3);
    int grow = grow0 + r; if (grow > growmax) grow = growmax;
    int c = (l & 7) ^ (l >> 3);            // inverse swizzle on source
    const u16* g = gbase + (size_t)grow * HID + c * 8;
    __builtin_amdgcn_global_load_lds((const __attribute__((address_space(1))) void*)g,
                                     (__attribute__((address_space(3))) void*)(lds + ch * 512),
                                     16, 0, 0);
  }
}

static __device__ __forceinline__ void compute128(const u16* As, const u16* Bs, int wr, int wc,
                                                  int li, int lg, f32x4 acc[4][4]) {
#pragma unroll
  for (int kk = 0; kk < 2; ++kk) {
    s16x8 af[4], bf[4];
#pragma unroll
    for (int mi = 0; mi < 4; ++mi) {
      int r = wr * 64 + mi * 16 + li;
      int c = (kk * 4 + lg) ^ (r & 7);
      af[mi] = *(const s16x8*)((const char*)As + r * 128 + c * 16);
    }
#pragma unroll
    for (int ni = 0; ni < 4; ++ni) {
      int r = wc * 64 + ni * 16 + li;
      int c = (kk * 4 + lg) ^ (r & 7);
      bf[ni] = *(const s16x8*)((const char*)Bs + r * 128 + c * 16);
    }
#pragma unroll
    for (int mi = 0; mi < 4; ++mi)
#pragma unroll
      for (int ni = 0; ni < 4; ++ni)
        acc[mi][ni] = __builtin_amdgcn_mfma_f32_16x16x32_bf16(af[mi], bf[ni], acc[mi][ni], 0, 0, 0);
  }
}

__global__ __launch_bounds__(256, 2) void qkv_gemm(const u16* __restrict__ Xb, const u16* __restrict__ Wt,
                                                   const float* __restrict__ bc, u16* __restrict__ Qw,
                                                   u16* __restrict__ Kw, u16* __restrict__ Vt) {
  __shared__ u16 LDSU[32768];               // 64 KiB union: staging buffers / V-transpose
  u16* As0 = LDSU;
  u16* Bs0 = LDSU + 8192;
  u16* As1 = LDSU + 16384;
  u16* Bs1 = LDSU + 24576;
  const int tid = threadIdx.x;
  const int w = tid >> 6, l = tid & 63;
  const int wr = w >> 1, wc = w & 1;        // 2x2 wave grid, 64x64 per wave
  const int lg = l >> 4, li = l & 15;

  // bijective XCD chunking (m204): nwg=1782, q=222, r=6
  const int lin = blockIdx.x;
  const int xcd = lin & 7;
  const int pos = lin >> 3;
  const int work = (xcd < 6 ? xcd * 223 : 6 * 223 + (xcd - 6) * 222) + pos;
  const int mt = work / NT, nt = work - mt * NT;
  const int arow0 = mt * 128, brow0 = nt * 128;

  f32x4 acc[4][4] = {};

  stage128(Xb, arow0, MROWS - 1, As0, w, l);
  stage128(Wt, brow0, NCAT - 1, Bs0, w, l);
  __syncthreads();

  for (int kt2 = 0; kt2 < 6; ++kt2) {
    const int kt = kt2 * 2;
    stage128(Xb + (kt + 1) * BK, arow0, MROWS - 1, As1, w, l);
    stage128(Wt + (kt + 1) * BK, brow0, NCAT - 1, Bs1, w, l);
    compute128(As0, Bs0, wr, wc, li, lg, acc);
    __syncthreads();
    if (kt2 < 5) {
      stage128(Xb + (kt + 2) * BK, arow0, MROWS - 1, As0, w, l);
      stage128(Wt + (kt + 2) * BK, brow0, NCAT - 1, Bs0, w, l);
    }
    compute128(As1, Bs1, wr, wc, li, lg, acc);
    __syncthreads();                        // also frees LDSU for the V epilogue
  }

  const int mblk = nt / 6;                 // 0=Q, 1=K, 2=V (block-uniform)
  float bcv[4];
#pragma unroll
  for (int ni = 0; ni < 4; ++ni) bcv[ni] = bc[brow0 + wc * 64 + ni * 16 + li];

  if (mblk < 2) {
    u16* __restrict__ dst = (mblk == 0) ? Qw : Kw;
    const float scale = (mblk == 0) ? 0.125f : 1.0f;
    int hv[4], dv[4];
#pragma unroll
    for (int ni = 0; ni < 4; ++ni) {
      int cloc = brow0 - mblk * HID + wc * 64 + ni * 16 + li;
      hv[ni] = cloc >> 6; dv[ni] = cloc & 63;
    }
#pragma unroll
    for (int mi = 0; mi < 4; ++mi) {
#pragma unroll
      for (int j = 0; j < 4; ++j) {
        int row = arow0 + wr * 64 + mi * 16 + lg * 4 + j;
        if (row < MROWS) {
          int b = row / SEQ, s = row - b * SEQ;
#pragma unroll
          for (int ni = 0; ni < 4; ++ni)
            dst[((size_t)(b * NH + hv[ni]) * SEQ + s) * DH + dv[ni]] = f2bf((acc[mi][ni][j] + bcv[ni]) * scale);
        }
      }
    }
  } else {
    // V: transpose via reused LDS (stride-68 pad), store s-contiguous
#pragma unroll
    for (int mi = 0; mi < 4; ++mi) {
#pragma unroll
      for (int ni = 0; ni < 4; ++ni) {
        u16x4 pk;
#pragma unroll
        for (int j = 0; j < 4; ++j) pk[j] = f2bf(acc[mi][ni][j] + bcv[ni]);
        *(u16x4*)&LDSU[w * 4352 + (ni * 16 + li) * 68 + mi * 16 + lg * 4] = pk;
      }
    }
    __syncthreads();
    const int cw0 = brow0 - 2 * HID;       // V-local col base (2 heads per tile)
#pragma unroll 4
    for (int p = 0; p < 64; ++p) {
      int i = p * 256 + tid;
      int r = i & 127, c = i >> 7;         // lane-consecutive r -> coalesced store
      int wq = ((r >> 6) << 1) | (c >> 6);
      u16 v = LDSU[wq * 4352 + (c & 63) * 68 + (r & 63)];
      int row = arow0 + r;
      if (row < MROWS) {
        int b = row / SEQ, s = row - b * SEQ;
        int cl = cw0 + c;
        int h = cl >> 6, d = cl & 63;
        Vt[((size_t)(b * NH + h) * DH + d) * VP + s] = v;
      }
    }
  }
}

// ---------------- fused attention: 1 BLOCK per bh (2 waves), K staged in LDS (r19-proven) ----------------
// LDS 41.4 KB -> 3 blocks/CU; 768 blocks = 3*256 EXACT (zero dispatch tail).
__global__ __launch_bounds__(128, 2) void attn(const u16* __restrict__ Qw, const u16* __restrict__ Kw,
                                               const u16* __restrict__ Vt, const u16* __restrict__ Bxt,
                                               float* __restrict__ out) {
  __shared__ u16 Klds[208 * 64];   // LDS 16B-chunk (r,c) holds K[r][ (c^(r&7))*8 .. +7 ]
  __shared__ u16 P[2][16 * 232];   // per-wave P transpose buffer
  const int tid = threadIdx.x;
  const int w = tid >> 6, l = tid & 63;
  const int lg = l >> 4, li = l & 15;
  const int lin = blockIdx.x;
  const int bh = (lin & 7) * 96 + (lin >> 3);   // 768 = 8*96 bijective XCD chunking
  const int b = bh / NH, h = bh - b * NH;

  const u16* Qb = Qw + (size_t)bh * QKSTRIDE;
  const u16* Kb = Kw + (size_t)bh * QKSTRIDE;
  const u16* Vb = Vt + (size_t)bh * DH * VP;

  // ---- stage K into LDS: 1664 16B chunks, wave w covers groups w*13..w*13+12 ----
#pragma unroll
  for (int i = 0; i < 13; ++i) {
    int ch = (w * 13 + i) * 64 + l;            // 0..1663
    int r = ch >> 3, c = ch & 7;
    int sc = c ^ (r & 7);                      // inverse swizzle on source
    __builtin_amdgcn_global_load_lds((const __attribute__((address_space(1))) void*)
                                         (Kb + (size_t)r * DH + sc * 8),
                                     (__attribute__((address_space(3))) void*)(Klds + (size_t)ch * 8),
                                     16, 0, 0);
  }
  // zero P tail cols 208..231 for this wave
  for (int t = l; t < 16 * 24; t += 64) {
    int rr = t / 24, cc = t - rr * 24;
    P[w][rr * 232 + 208 + cc] = 0;
  }
  __syncthreads();                             // K visible to both waves

  for (int it = 0; it < 7; ++it) {
    const int qf = w + 2 * it;                 // w0: 0,2,..,12 ; w1: 1,3,..,11
    if (qf >= 13) break;                       // wave-uniform

    const u16x4* Bht = (const u16x4*)Bxt + ((size_t)(h * 13 + qf) * 13) * 64 + l;

    // Q frags (rows may over-read into pad: finite, outputs guarded)
    s16x8 a0 = *(const s16x8*)(Qb + (size_t)(qf * 16 + li) * DH + lg * 8);
    s16x8 a1 = *(const s16x8*)(Qb + (size_t)(qf * 16 + li) * DH + 32 + lg * 8);

    // batched bias loads — tiled layout: one coalesced 512B segment per kf
    u16x4 bb[13];
#pragma unroll
    for (int kf = 0; kf < 13; ++kf)
      bb[kf] = Bht[kf * 64];

    // QK^T with K frags from LDS (swizzled, conflict-free)
    f32x4 S[13];
#pragma unroll
    for (int kf = 0; kf < 13; ++kf) {
      int r = kf * 16 + li;
      s16x8 k0 = *(const s16x8*)((const char*)Klds + r * 128 + ((lg) ^ (r & 7)) * 16);
      s16x8 k1 = *(const s16x8*)((const char*)Klds + r * 128 + ((4 + lg) ^ (r & 7)) * 16);
      f32x4 c = {};
      c = __builtin_amdgcn_mfma_f32_16x16x32_bf16(a0, k0, c, 0, 0, 0);
      c = __builtin_amdgcn_mfma_f32_16x16x32_bf16(a1, k1, c, 0, 0, 0);
#pragma unroll
      for (int j = 0; j < 4; ++j)
        S[kf][j] = c[j] + bf2f(bb[kf][j]);
    }

    // softmax over 13 regs x 16 lanes (per 16-lane group)
    float rinv[4];
#pragma unroll
    for (int j = 0; j < 4; ++j) {
      float m = S[0][j];
#pragma unroll
      for (int kf = 1; kf < 13; ++kf) m = fmaxf(m, S[kf][j]);
      m = fmaxf(m, __shfl_xor(m, 1));
      m = fmaxf(m, __shfl_xor(m, 2));
      m = fmaxf(m, __shfl_xor(m, 4));
      m = fmaxf(m, __shfl_xor(m, 8));
      float sum = 0.f;
#pragma unroll
      for (int kf = 0; kf < 13; ++kf) {
        float p = __expf(S[kf][j] - m);
        S[kf][j] = p;
        sum += p;
      }
      sum += __shfl_xor(sum, 1);
      sum += __shfl_xor(sum, 2);
      sum += __shfl_xor(sum, 4);
      sum += __shfl_xor(sum, 8);
      rinv[j] = 1.0f / sum;
    }

    // transpose P into this wave's LDS buffer (bf16)
#pragma unroll
    for (int kf = 0; kf < 13; ++kf)
#pragma unroll
      for (int j = 0; j < 4; ++j)
        P[w][(lg * 4 + j) * 232 + kf * 16 + li] = f2bf(S[kf][j]);

    // PV with 4-deep V-frag pipeline (V from global/L2)
    s16x8 vb[4];
#pragma unroll
    for (int p = 0; p < 4; ++p)
      vb[p] = *(const s16x8*)(Vb + (size_t)((p / 7) * 16 + li) * VP + (p % 7) * 32 + lg * 8);
    f32x4 o[4];
#pragma unroll
    for (int nf = 0; nf < 4; ++nf) {
      f32x4 c = {};
#pragma unroll
      for (int t = 0; t < 7; ++t) {
        const int u = nf * 7 + t, slot = u & 3;
        s16x8 pa = *(const s16x8*)(&P[w][li * 232 + t * 32 + lg * 8]);
        c = __builtin_amdgcn_mfma_f32_16x16x32_bf16(pa, vb[slot], c, 0, 0, 0);
        if (u + 4 < 28) {
          const int u2 = u + 4;
          vb[slot] = *(const s16x8*)(Vb + (size_t)((u2 / 7) * 16 + li) * VP + (u2 % 7) * 32 + lg * 8);
        }
      }
      o[nf] = c;
    }
#pragma unroll
    for (int nf = 0; nf < 4; ++nf) {
#pragma unroll
      for (int j = 0; j < 4; ++j) {
        int q = qf * 16 + lg * 4 + j;
        if (q < SEQ)
          out[((size_t)(b * SEQ + q)) * HID + h * DH + nf * 16 + li] = o[nf][j] * rinv[j];
      }
    }
  }
}

extern "C" void kernel_launch(void* const* d_in, const int* in_sizes, int n_in,
                              void* d_out, int out_size, void* d_ws, size_t ws_size,
                              hipStream_t stream) {
  const float* hidden = (const float*)d_in[0];
  const float* Wq = (const float*)d_in[1];
  const float* bq = (const float*)d_in[2];
  const float* Wk = (const float*)d_in[3];
  const float* Wv = (const float*)d_in[4];
  const float* bv = (const float*)d_in[5];
  const float* btab = (const float*)d_in[6];
  float* out = (float*)d_out;

  // workspace layout (peak 84,712,576 B, within proven budget):
  char* ws = (char*)d_ws;
  u16* Xb  = (u16*)(ws);                       // [0, 19,365,888)   12608*768*2
  u16* Wt  = (u16*)(ws + 19365888);            // [.., 22,904,832)  2304*768*2
  float* bc = (float*)(ws + 22904832);         // [.., 22,914,048)  2304*4
  u16* Bxt = (u16*)(ws + 22914048);            // [.., 23,952,384)  12*13*13*64*4 u16 = 1,038,336 B
  u16* Qw  = (u16*)(ws + 23952512);            // [.., 43,322,496)  (768*197+32)*64*2
  u16* Kw  = (u16*)(ws + 43322496);            // [.., 62,692,480)  (768*197+32)*64*2
  u16* Vt  = (u16*)(ws + 62692480);            // [.., 84,712,576)  768*64*224*2

  prep_all<<<dim3(PB_E), dim3(256), 0, stream>>>(hidden, Wq, Wk, Wv, bq, bv, btab, Xb, Wt, bc, Bxt);
  qkv_gemm<<<dim3(NWG), dim3(256), 0, stream>>>(Xb, Wt, bc, Qw, Kw, Vt);
  attn<<<dim3(768), dim3(128), 0, stream>>>(Qw, Kw, Vt, Bxt, out);
}